// Round 13
// baseline (154.066 us; speedup 1.0000x reference)
//
#include <hip/hip_runtime.h>

// B=4, C=64, H=W=64, N=4096, GROUPS=32 (2 ch/group), R=4.
// ws layout (bytes):
#define STATS_OFF 0                       // [1024][5] fp32 partial sums (bc*4+chunk)
#define WQB_OFF   32768                   // bf16 wq*qscale [o][c] 8KB
#define WKB_OFF   40960                   // bf16 wk
#define WVB_OFF   49152                   // bf16 wv
#define Q_OFF     57344                   // [bh][n][c] bf16, 4MB (q pre-scaled)
#define K_OFF     (Q_OFF + 4194304)       // [bh][n][c] bf16, 4MB
#define V_OFF     (K_OFF + 4194304)       // [b][c][n]  bf16, 2MB
#define PO_OFF    (V_OFF + 2097152)       // [bh][js][n][c] bf16 partials, then pl fp32

#define QSCALE 0.18033688f                // 0.125 * log2(e)
// XOR swizzle (8-element granularity) -> balanced LDS bank phases for b128/b64 frag reads
#define SWZ(r) ((((r) & 7) << 3) ^ (((r) & 8) << 1))

typedef __attribute__((ext_vector_type(8))) short  short8;
typedef __attribute__((ext_vector_type(4))) short  s16x4;
typedef __attribute__((ext_vector_type(2))) unsigned int u32x2;
typedef __attribute__((ext_vector_type(4))) float  f32x4;

#if __has_builtin(__builtin_amdgcn_exp2f)
__device__ inline float fexp2(float x) { return __builtin_amdgcn_exp2f(x); }  // raw v_exp_f32
#else
__device__ inline float fexp2(float x) { return exp2f(x); }
#endif

__device__ inline ushort f2b(float f) {   // round-half-up to bf16
  return (ushort)((__float_as_uint(f) + 0x8000u) >> 16);
}
__device__ inline unsigned pack2(float x, float y) {  // bf16(x) | bf16(y)<<16
  unsigned ux = __float_as_uint(x) + 0x8000u;
  unsigned uy = __float_as_uint(y) + 0x8000u;
  return __builtin_amdgcn_perm(uy, ux, 0x07060302);
}
__device__ inline float b2f(ushort u) { return __uint_as_float(((unsigned)u) << 16); }

__device__ inline f32x4 mfma16(short8 a, short8 b, f32x4 c) {
  return __builtin_amdgcn_mfma_f32_16x16x32_bf16(a, b, c, 0, 0, 0);
}

__device__ inline float wsum64(float v) {
  #pragma unroll
  for (int o = 32; o > 0; o >>= 1) v += __shfl_down(v, o, 64);
  return v;
}

// ---------------- kernel 1: per-(b,c) partial sums + bf16 weight conversion ----------------
__global__ __launch_bounds__(256) void sc_stats(const float* __restrict__ x1,
                                                const float* __restrict__ x2,
                                                float* __restrict__ stats,
                                                const float* __restrict__ wq,
                                                const float* __restrict__ wk,
                                                const float* __restrict__ wv,
                                                ushort* __restrict__ wqb,
                                                ushort* __restrict__ wkb,
                                                ushort* __restrict__ wvb) {
  int blk = blockIdx.x, t = threadIdx.x;  // 1024 = bc*4 + chunk
  int bc = blk >> 2, chunk = blk & 3;
  const float4* p1 = (const float4*)(x1 + (size_t)bc * 4096 + chunk * 1024);
  const float4* p2 = (const float4*)(x2 + (size_t)bc * 4096 + chunk * 1024);
  float4 a = p1[t], b = p2[t];
  float s1 = a.x + a.y + a.z + a.w;
  float q1 = a.x*a.x + a.y*a.y + a.z*a.z + a.w*a.w;
  float s2 = b.x + b.y + b.z + b.w;
  float q2 = b.x*b.x + b.y*b.y + b.z*b.z + b.w*b.w;
  float p12 = a.x*b.x + a.y*b.y + a.z*b.z + a.w*b.w;
  s1 = wsum64(s1); q1 = wsum64(q1); s2 = wsum64(s2); q2 = wsum64(q2); p12 = wsum64(p12);
  __shared__ float red[4][5];
  int w = t >> 6, ln = t & 63;
  if (ln == 0) { red[w][0] = s1; red[w][1] = q1; red[w][2] = s2; red[w][3] = q2; red[w][4] = p12; }
  __syncthreads();
  if (t < 5) {
    float acc = 0;
    #pragma unroll
    for (int ww = 0; ww < 4; ww++) acc += red[ww][t];
    stats[(size_t)blk * 5 + t] = acc;
  }
  if (blk >= 976) {     // parallel bf16 weight conversion (independent of stats)
    int idx = (blk - 976) * 256 + t;
    int arr = idx >> 12, e = idx & 4095;
    if (arr == 0)      wqb[e] = f2b(wq[e] * QSCALE);
    else if (arr == 1) wkb[e] = f2b(wk[e]);
    else               wvb[e] = f2b(wv[e]);
  }
}

// ------------- kernel 2: GN + 1x1 conv projections via MFMA, inline GN fold -------------
__global__ __launch_bounds__(256) void sc_proj(const float* __restrict__ x1, const float* __restrict__ x2,
    const float* __restrict__ stats,
    const float* __restrict__ gamma, const float* __restrict__ beta,
    const float* __restrict__ wq, const float* __restrict__ bq,
    const float* __restrict__ wk, const float* __restrict__ bk,
    const float* __restrict__ wv, const float* __restrict__ bv,
    const ushort* __restrict__ wqb, const ushort* __restrict__ wkb, const ushort* __restrict__ wvb,
    ushort* __restrict__ qout, ushort* __restrict__ kout, ushort* __restrict__ vout) {
  int pt = blockIdx.x, src = blockIdx.y, b = blockIdx.z, t = threadIdx.x;
  __shared__ ushort xlds[64 * 66];   // xn tile [p][c], bf16
  __shared__ ushort olds[64 * 66];   // output assembly tile
  __shared__ float sS[64], sQ[64], sa[64], sd[64], sbias[2][64];
  if (t < 64) {                      // per-channel sums for this src
    float a1 = 0, a2 = 0, a3 = 0, a4 = 0, a5 = 0;
    #pragma unroll
    for (int ch = 0; ch < 4; ch++) {
      const float* sp = stats + (size_t)((b * 64 + t) * 4 + ch) * 5;
      a1 += sp[0]; a2 += sp[1]; a3 += sp[2]; a4 += sp[3]; a5 += sp[4];
    }
    float S, Q;
    if (src == 0)      { S = a1 + a3; Q = a2 + a4 + 2.f * a5; }
    else if (src == 1) { S = a1; Q = a2; }
    else               { S = a3; Q = a4; }
    sS[t] = S; sQ[t] = Q;
  }
  __syncthreads();
  if (t < 64) {                      // 2-channel group fold
    float S = sS[t] + sS[t ^ 1], Q = sQ[t] + sQ[t ^ 1];
    float mean = S * (1.f / 8192.f);
    float var  = Q * (1.f / 8192.f) - mean * mean;
    float rstd = rsqrtf(var + 1e-6f);
    float a = gamma[t] * rstd;
    sa[t] = a;
    sd[t] = beta[t] - mean * a;
  }
  __syncthreads();
  {
    int c = t >> 2, pq = (t & 3) * 16;
    const float* px1 = x1 + ((size_t)(b*64 + c))*4096 + pt*64 + pq;
    const float* px2 = x2 + ((size_t)(b*64 + c))*4096 + pt*64 + pq;
    float av = sa[c];
    #pragma unroll
    for (int k4 = 0; k4 < 4; k4++) {
      float4 v1 = *(const float4*)(px1 + 4*k4);
      float xv[4];
      if (src == 1) { xv[0]=v1.x; xv[1]=v1.y; xv[2]=v1.z; xv[3]=v1.w; }
      else {
        float4 v2 = *(const float4*)(px2 + 4*k4);
        if (src == 2) { xv[0]=v2.x; xv[1]=v2.y; xv[2]=v2.z; xv[3]=v2.w; }
        else { xv[0]=v1.x+v2.x; xv[1]=v1.y+v2.y; xv[2]=v1.z+v2.z; xv[3]=v1.w+v2.w; }
      }
      #pragma unroll
      for (int k = 0; k < 4; k++)
        xlds[(pq + 4*k4 + k)*66 + c] = f2b(av * xv[k]);
    }
  }
  int nbias = (src == 0) ? 64 : 128;
  if (t < nbias) {                   // bias' = W*d + bias (parallel across all 768 blocks)
    int proj = t >> 6, o = t & 63;
    const float* W  = (src == 0) ? wv : (proj == 0 ? wq : wk);
    const float* bs = (src == 0) ? bv : (proj == 0 ? bq : bk);
    float acc = bs[o];
    for (int cc = 0; cc < 64; cc++) acc += W[o*64+cc] * sd[cc];
    if (src != 0 && proj == 0) acc *= QSCALE;
    sbias[proj][o] = acc;
  }
  __syncthreads();
  int wave = t >> 6, lane = t & 63, quad = lane >> 4, l15 = lane & 15;
  int orow = t >> 2, ocol = (t & 3) * 16;   // coalesced write-out mapping
  if (src == 0) {
    const ushort* ap = wvb + (wave*16 + l15)*64 + quad*8;
    short8 a0 = *(const short8*)ap;
    short8 a1 = *(const short8*)(ap + 32);
    f32x4 cinit;
    #pragma unroll
    for (int r = 0; r < 4; r++) cinit[r] = sbias[0][wave*16 + quad*4 + r];
    #pragma unroll
    for (int s = 0; s < 4; s++) {
      const ushort* bp = xlds + (s*16 + l15)*66 + quad*8;
      short8 b0 = *(const short8*)bp;
      short8 b1 = *(const short8*)(bp + 32);
      f32x4 acc = mfma16(a0, b0, cinit);
      acc = mfma16(a1, b1, acc);
      #pragma unroll
      for (int r = 0; r < 4; r++)
        olds[(wave*16 + quad*4 + r)*66 + s*16 + l15] = f2b(acc[r]);   // [o][p]
    }
    __syncthreads();
    uint4 w0 = *(const uint4*)&olds[orow*66 + ocol];
    uint4 w1 = *(const uint4*)&olds[orow*66 + ocol + 8];
    ushort* dst = vout + ((size_t)(b*64 + orow))*4096 + pt*64 + ocol;
    *(uint4*)dst = w0; *(uint4*)(dst + 8) = w1;
  } else {
    int bh = b*2 + (src - 1);
    const ushort* ap = xlds + (wave*16 + l15)*66 + quad*8;
    short8 a0 = *(const short8*)ap;
    short8 a1 = *(const short8*)(ap + 32);
    #pragma unroll
    for (int proj = 0; proj < 2; proj++) {
      const ushort* Wb = proj == 0 ? wqb : wkb;
      ushort* dst = proj == 0 ? qout : kout;
      #pragma unroll
      for (int s = 0; s < 4; s++) {
        const ushort* bp = Wb + (s*16 + l15)*64 + quad*8;
        short8 b0 = *(const short8*)bp;
        short8 b1 = *(const short8*)(bp + 32);
        float bb = sbias[proj][s*16 + l15];
        f32x4 acc = {bb, bb, bb, bb};
        acc = mfma16(a0, b0, acc);
        acc = mfma16(a1, b1, acc);
        #pragma unroll
        for (int r = 0; r < 4; r++)
          olds[(wave*16 + quad*4 + r)*66 + s*16 + l15] = f2b(acc[r]);  // [p][o]
      }
      __syncthreads();
      uint4 w0 = *(const uint4*)&olds[orow*66 + ocol];
      uint4 w1 = *(const uint4*)&olds[orow*66 + ocol + 8];
      ushort* dp = dst + ((size_t)bh*4096 + pt*64 + orow)*64 + ocol;
      *(uint4*)dp = w0; *(uint4*)(dp + 8) = w1;
      if (proj == 0) __syncthreads();   // olds reused by proj 1
    }
  }
}

// ------------- kernel 3: flash attention, double-buffered LDS, ONE barrier per j-tile -------------
// grid 8*16*njs. R12 compute body; staging writes go to the other buffer concurrent with
// compute. Hazards: at sync(jt), buf[jt&1] writes (iter jt-1) complete; buf[(jt+1)&1]'s
// last readers ran in iter jt-1 — both ordered by the single barrier.
// launch_bounds(256,2): VGPR cap 128, body uses ~110. LDS 32KB -> 4 blocks/CU.
__global__ __launch_bounds__(256, 2) void sc_flash(const ushort* __restrict__ qg,
                                                   const ushort* __restrict__ kg,
                                                   const ushort* __restrict__ vg,
                                                   ushort* __restrict__ po,
                                                   float* __restrict__ pl,
                                                   int jsbits) {
  int blk = blockIdx.x;
  int bh = blk & 7, rest = blk >> 3;
  int njs = 1 << jsbits, njt = 64 >> jsbits;
  int js = rest & (njs - 1), itile = rest >> jsbits;   // itile 0..15
  int jbase = js * (njt << 6);
  int b = bh >> 1;
  int t = threadIdx.x, wave = t >> 6, lane = t & 63, quad = lane >> 4, l15 = lane & 15;
  int i0 = itile * 256 + wave * 64;

  __shared__ ushort Klds[2 * 4096];      // [buf][j][c^swz(j)]
  __shared__ ushort Vlds[2 * 4096];      // [buf][c][j^swz(c)]

  short8 Qb[4][2];
  #pragma unroll
  for (int ib = 0; ib < 4; ib++) {
    const ushort* qp = qg + ((size_t)bh * 4096 + i0 + ib * 16 + l15) * 64 + quad * 8;
    Qb[ib][0] = *(const short8*)qp;
    Qb[ib][1] = *(const short8*)(qp + 32);
  }

  f32x4 O[4][4]; const f32x4 zero4 = {0.f, 0.f, 0.f, 0.f};
  #pragma unroll
  for (int ib = 0; ib < 4; ib++)
    #pragma unroll
    for (int cb = 0; cb < 4; cb++) O[ib][cb] = zero4;
  float lsum[4] = {0.f, 0.f, 0.f, 0.f};

  int sr = t >> 2, sc = (t & 3) * 16;
  int swzs = SWZ(sr);
  int swzl = SWZ(l15);
  const ushort* ksrc = kg + ((size_t)bh * 4096 + jbase + sr) * 64 + sc;
  const ushort* vsrc = vg + ((size_t)(b * 64 + sr)) * 4096 + jbase + sc;
  int kdo0 = sr * 64 + (sc ^ swzs);
  int kdo1 = sr * 64 + ((sc + 8) ^ swzs);

  // tile 0: load + write buf0 (reads happen only after the first in-loop barrier)
  uint4 kr0 = *(const uint4*)ksrc, kr1 = *(const uint4*)(ksrc + 8);
  uint4 vr0 = *(const uint4*)vsrc, vr1 = *(const uint4*)(vsrc + 8);
  ksrc += 4096; vsrc += 64;
  *(uint4*)(Klds + kdo0) = kr0; *(uint4*)(Klds + kdo1) = kr1;
  *(uint4*)(Vlds + kdo0) = vr0; *(uint4*)(Vlds + kdo1) = vr1;
  if (njt > 1) {                         // tile 1 into regs
    kr0 = *(const uint4*)ksrc; kr1 = *(const uint4*)(ksrc + 8);
    vr0 = *(const uint4*)vsrc; vr1 = *(const uint4*)(vsrc + 8);
    ksrc += 4096; vsrc += 64;
  }

  #pragma unroll 1
  for (int jt = 0; jt < njt; jt++) {
    __syncthreads();                     // buf[jt&1] ready; buf[(jt+1)&1] free
    if (jt + 1 < njt) {                  // stage tile jt+1 into the other buffer
      int bo = ((jt + 1) & 1) << 12;
      *(uint4*)(Klds + bo + kdo0) = kr0; *(uint4*)(Klds + bo + kdo1) = kr1;
      *(uint4*)(Vlds + bo + kdo0) = vr0; *(uint4*)(Vlds + bo + kdo1) = vr1;
    }
    if (jt + 2 < njt) {                  // issue tile jt+2 loads; land during compute
      kr0 = *(const uint4*)ksrc; kr1 = *(const uint4*)(ksrc + 8);
      vr0 = *(const uint4*)vsrc; vr1 = *(const uint4*)(vsrc + 8);
      ksrc += 4096; vsrc += 64;
    }
    const ushort* Kb = Klds + ((jt & 1) << 12);
    const ushort* Vb = Vlds + ((jt & 1) << 12);

    #pragma unroll
    for (int s = 0; s < 4; s++) {
      int rowK = (s * 16 + l15) * 64;
      short8 ka0 = *(const short8*)&Kb[rowK + ((quad * 8) ^ swzl)];
      short8 ka1 = *(const short8*)&Kb[rowK + ((quad * 8 + 32) ^ swzl)];
      f32x4 S[4];
      #pragma unroll
      for (int ib = 0; ib < 4; ib++) {
        f32x4 acc = mfma16(ka0, Qb[ib][0], zero4);
        S[ib] = mfma16(ka1, Qb[ib][1], acc);
      }
      s16x4 vbf[4];
      #pragma unroll
      for (int cb = 0; cb < 4; cb++)
        vbf[cb] = *(const s16x4*)&Vb[(cb * 16 + l15) * 64 + ((s * 16 + quad * 4) ^ swzl)];
      #pragma unroll
      for (int ib = 0; ib < 4; ib++) {
        float p0 = fexp2(S[ib][0]);
        float p1 = fexp2(S[ib][1]);
        float p2 = fexp2(S[ib][2]);
        float p3 = fexp2(S[ib][3]);
        lsum[ib] += (p0 + p1) + (p2 + p3);
        u32x2 wpk = {pack2(p0, p1), pack2(p2, p3)};
        s16x4 Pb = __builtin_bit_cast(s16x4, wpk);
        #pragma unroll
        for (int cb = 0; cb < 4; cb++)
          O[ib][cb] = __builtin_amdgcn_mfma_f32_16x16x16bf16_1k(Pb, vbf[cb], O[ib][cb], 0, 0, 0);
      }
    }
  }

  size_t slice = (size_t)(bh * njs + js) * 4096;
  #pragma unroll
  for (int ib = 0; ib < 4; ib++) {
    float lv = lsum[ib];
    lv += __shfl_xor(lv, 16, 64);
    lv += __shfl_xor(lv, 32, 64);
    if (quad == 0) pl[slice + i0 + ib * 16 + l15] = lv;
    #pragma unroll
    for (int cb = 0; cb < 4; cb++)
      #pragma unroll
      for (int r = 0; r < 4; r++)
        po[(slice + i0 + ib * 16 + quad * 4 + r) * 64 + cb * 16 + l15] = f2b(O[ib][cb][r]);
  }
}

// ------------- kernel 4: partial reduce + normalize + SE-gated blend, inline SE -------------
// grid (64 itile, 4 b, 2 chalf). Each block recomputes its b's SE sigmoid from stats.
__global__ __launch_bounds__(256) void sc_combine(const float* __restrict__ x1, const float* __restrict__ x2,
                                                  const ushort* __restrict__ po, const float* __restrict__ pl,
                                                  const float* __restrict__ stats,
                                                  const float* __restrict__ w1, const float* __restrict__ w2,
                                                  float* __restrict__ out, int jsbits) {
  int njs = 1 << jsbits;
  int itile = blockIdx.x, b = blockIdx.y, ch = blockIdx.z, t = threadIdx.x;
  __shared__ float hl[2][32 * 65];   // [head][c-local][p]
  __shared__ float smu[64], syr[4], ssey[64];
  if (t < 64) {                      // spatial mean of x = x1+x2 for channel t of batch b
    float s = 0;
    #pragma unroll
    for (int chk = 0; chk < 4; chk++) {
      const float* sp = stats + (size_t)((b * 64 + t) * 4 + chk) * 5;
      s += sp[0] + sp[2];
    }
    smu[t] = s * (1.f / 4096.f);
  }
  __syncthreads();
  if (t < 4) {                       // SE layer 1 + relu
    float acc = 0.f;
    for (int cc = 0; cc < 64; cc++) acc += w1[t*64+cc] * smu[cc];
    syr[t] = fmaxf(acc, 0.f);
  }
  __syncthreads();
  if (t < 64) {                      // SE layer 2 + sigmoid
    float acc = 0.f;
    #pragma unroll
    for (int r = 0; r < 4; r++) acc += w2[t*4+r] * syr[r];
    ssey[t] = 1.f / (1.f + fexp2(-acc * 1.44269504f));
  }
  #pragma unroll
  for (int head = 0; head < 2; head++) {
    int bh = b * 2 + head;
    int i = t >> 2, c8 = (t & 3) * 8;
    float sum[8];
    #pragma unroll
    for (int k = 0; k < 8; k++) sum[k] = 0.f;
    float lacc = 0.f;
    for (int js = 0; js < njs; js++) {
      size_t base = ((size_t)(bh * njs + js)) * 4096;
      uint4 u = *(const uint4*)(po + base * 64 + (size_t)(itile * 64 + i) * 64 + ch * 32 + c8);
      const ushort* us = (const ushort*)&u;
      #pragma unroll
      for (int k = 0; k < 8; k++) sum[k] += b2f(us[k]);
      lacc += pl[base + itile * 64 + i];
    }
    float inv = 1.f / lacc;
    #pragma unroll
    for (int k = 0; k < 8; k++) hl[head][(c8 + k) * 65 + i] = sum[k] * inv;
  }
  __syncthreads();
  #pragma unroll
  for (int it = 0; it < 8; it++) {
    int idx = it * 256 + t;
    int cl = idx >> 6, p = idx & 63;
    int c = ch * 32 + cl;
    size_t gi = ((size_t)(b * 64 + c)) * 4096 + itile * 64 + p;
    float xv = x1[gi] + x2[gi];
    float sig = 1.f / (1.f + fexp2(-xv * ssey[c] * 1.44269504f));
    float h1 = hl[0][cl * 65 + p], h2 = hl[1][cl * 65 + p];
    out[gi] = 2.f * (h1 * sig + h2 * (1.f - sig));
  }
}

extern "C" void kernel_launch(void* const* d_in, const int* in_sizes, int n_in,
                              void* d_out, int out_size, void* d_ws, size_t ws_size,
                              hipStream_t stream) {
  (void)in_sizes; (void)n_in; (void)out_size;
  const float* x1    = (const float*)d_in[0];
  const float* x2    = (const float*)d_in[1];
  const float* se_w1 = (const float*)d_in[2];
  const float* se_w2 = (const float*)d_in[3];
  const float* gamma = (const float*)d_in[4];
  const float* beta  = (const float*)d_in[5];
  const float* wq    = (const float*)d_in[6];
  const float* bq    = (const float*)d_in[7];
  const float* wk    = (const float*)d_in[8];
  const float* bk    = (const float*)d_in[9];
  const float* wv    = (const float*)d_in[10];
  const float* bv    = (const float*)d_in[11];
  float* out = (float*)d_out;
  char* ws = (char*)d_ws;
  float*  stats = (float*)(ws + STATS_OFF);
  ushort* wqb   = (ushort*)(ws + WQB_OFF);
  ushort* wkb   = (ushort*)(ws + WKB_OFF);
  ushort* wvb   = (ushort*)(ws + WVB_OFF);
  ushort* qb    = (ushort*)(ws + Q_OFF);
  ushort* kb    = (ushort*)(ws + K_OFF);
  ushort* vb    = (ushort*)(ws + V_OFF);

  // js split: largest of {8,4,2} whose partials fit the workspace (ws_size fixed per process).
  int jsbits = 1;
  for (int jb = 3; jb >= 2; jb--) {
    size_t need = (size_t)PO_OFF + ((size_t)8 * 4096 * 64 * 2 + (size_t)8 * 4096 * 4) * (1u << jb);
    if (ws_size >= need) { jsbits = jb; break; }
  }
  int njs = 1 << jsbits;
  ushort* pob = (ushort*)(ws + PO_OFF);
  float*  plb = (float*)(ws + PO_OFF + (size_t)8 * njs * 4096 * 64 * 2);

  sc_stats  <<<1024, 256, 0, stream>>>(x1, x2, stats, wq, wk, wv, wqb, wkb, wvb);
  sc_proj   <<<dim3(64, 3, 4), 256, 0, stream>>>(x1, x2, stats, gamma, beta,
                                                 wq, bq, wk, bk, wv, bv,
                                                 wqb, wkb, wvb, qb, kb, vb);
  sc_flash  <<<8 * 16 * njs, 256, 0, stream>>>(qb, kb, vb, pob, plb, jsbits);
  sc_combine<<<dim3(64, 4, 2), 256, 0, stream>>>(x1, x2, pob, plb, stats,
                                                 se_w1, se_w2, out, jsbits);
}